// Round 10
// baseline (277.675 us; speedup 1.0000x reference)
//
#include <hip/hip_runtime.h>
#include <hip/hip_bf16.h>

typedef __attribute__((ext_vector_type(8))) short bf16x8;
typedef __attribute__((ext_vector_type(4))) float f32x4;
typedef unsigned short u16;

#define DIMC 1024
#define NHEAD 16
#define HDIM 64
#define NB 4
#define NQ 4096
#define NS 512

#define LOG2E 1.44269504f

#if __has_builtin(__builtin_amdgcn_exp2f)
#define EXP2F(x) __builtin_amdgcn_exp2f(x)
#else
#define EXP2F(x) __expf(0.69314718f * (x))
#endif

#if __has_builtin(__builtin_amdgcn_rcpf)
#define RCPF(x) __builtin_amdgcn_rcpf(x)
#else
#define RCPF(x) (1.0f / (x))
#endif

__device__ __forceinline__ u16 f2bf(float f) {
  __hip_bfloat16 h = __float2bfloat16(f);
  return *reinterpret_cast<u16*>(&h);
}

__device__ __forceinline__ unsigned pack_bf2(float a, float b) {
  __hip_bfloat162 h2 = __float22bfloat162_rn(make_float2(a, b));
  return *reinterpret_cast<unsigned*>(&h2);
}

__device__ __forceinline__ void gload_lds16(const void* g, void* s) {
  __builtin_amdgcn_global_load_lds(
      (const __attribute__((address_space(1))) void*)g,
      (__attribute__((address_space(3))) void*)s, 16, 0, 0);
}

// ---------------- fused preprocessing kernel ----------------

__device__ __forceinline__ void cvt_body(const float* __restrict__ in,
                                         u16* __restrict__ out, int base, int nblk,
                                         int n4) {
  const int stride = nblk * 256;
  for (int i = base * 256 + threadIdx.x; i < n4; i += stride) {
    float4 v = *(const float4*)(in + (size_t)i * 4);
    ushort4 o;
    o.x = f2bf(v.x); o.y = f2bf(v.y); o.z = f2bf(v.z); o.w = f2bf(v.w);
    *(ushort4*)(out + (size_t)i * 4) = o;
  }
}

__global__ void prep_kernel(const float* __restrict__ x, const float* __restrict__ ctx,
                            const int* __restrict__ cmask,
                            const float* __restrict__ q_w, const float* __restrict__ kv_w,
                            const float* __restrict__ proj_w,
                            u16* __restrict__ x_bf, u16* __restrict__ ctx_bf,
                            u16* __restrict__ qwT, u16* __restrict__ kvwT,
                            u16* __restrict__ pwT, float* __restrict__ maskf) {
  __shared__ float t[32][33];
  const int bid = blockIdx.x;
  if (bid < 2048) {
    cvt_body(x, x_bf, bid, 2048, 16777216 / 4);
    return;
  }
  if (bid < 2560) {
    cvt_body(ctx, ctx_bf, bid - 2048, 512, 2097152 / 4);
    return;
  }
  if (bid >= 6656) {
    const int i = (bid - 6656) * 256 + threadIdx.x;
    if (i < NB * NS) maskf[i] = cmask[i] ? -1e30f : 0.0f;
    return;
  }
  // transpose jobs: W [K][N] f32 -> WT [N][K] bf16
  const float* W;
  u16* WT;
  int K, N, local;
  if (bid < 3584) {
    W = q_w; WT = qwT; K = 1024; N = 1024; local = bid - 2560;
  } else if (bid < 5632) {
    W = kv_w; WT = kvwT; K = 1024; N = 2048; local = bid - 3584;
  } else {
    W = proj_w; WT = pwT; K = 1024; N = 1024; local = bid - 5632;
  }
  const int nbx = N >> 5;
  const int bx = (local % nbx) * 32;
  const int by = (local / nbx) * 32;
  const int tx = threadIdx.x & 31, ty = threadIdx.x >> 5;  // ty 0..7
#pragma unroll
  for (int i = 0; i < 32; i += 8)
    t[ty + i][tx] = W[(size_t)(by + ty + i) * N + bx + tx];
  __syncthreads();
#pragma unroll
  for (int i = 0; i < 32; i += 8)
    WT[(size_t)(bx + ty + i) * K + by + tx] = f2bf(t[tx][ty + i]);
}

// ---------------- 128-tile bf16 GEMM (KV scatter only) ----------------

__launch_bounds__(256)
__global__ void gemm_kv(const u16* __restrict__ A, const u16* __restrict__ BT,
                        const float* __restrict__ bias, u16* __restrict__ Kout,
                        u16* __restrict__ VTout, int M, int N, int K) {
  __shared__ __align__(16) u16 As[128 * 32];
  __shared__ __align__(16) u16 Bs[128 * 32];
  const int tid = threadIdx.x;
  const int w = tid >> 6, l = tid & 63;
  const int wr = w >> 1, wc = w & 1;
  const int fr = l & 15, fhi = l >> 4;

  const int nwg = gridDim.x * gridDim.y;
  const int o = blockIdx.y * gridDim.x + blockIdx.x;
  const int tIdx = (o & 7) * (nwg >> 3) + (o >> 3);
  const int m0 = (tIdx / gridDim.x) * 128;
  const int n0 = (tIdx % gridDim.x) * 128;

  const f32x4 fz = {0.f, 0.f, 0.f, 0.f};
  f32x4 acc[4][4];
#pragma unroll
  for (int mt = 0; mt < 4; mt++)
#pragma unroll
    for (int nt = 0; nt < 4; nt++) acc[mt][nt] = fz;

  const int f0 = w * 2048 + l * 16;
  const int f1 = f0 + 1024;
  const int ar0 = f0 >> 6, ac0 = (f0 & 63) >> 1;
  const int ar1 = f1 >> 6, ac1 = (f1 & 63) >> 1;
  const u16* Ag0 = A + (size_t)(m0 + ar0) * K + ac0;
  const u16* Ag1 = A + (size_t)(m0 + ar1) * K + ac1;
  const u16* Bg0 = BT + (size_t)(n0 + ar0) * K + ac0;
  const u16* Bg1 = BT + (size_t)(n0 + ar1) * K + ac1;

  for (int k0 = 0; k0 < K; k0 += 32) {
    gload_lds16(Ag0 + k0, &As[w * 1024]);
    gload_lds16(Ag1 + k0, &As[w * 1024 + 512]);
    gload_lds16(Bg0 + k0, &Bs[w * 1024]);
    gload_lds16(Bg1 + k0, &Bs[w * 1024 + 512]);
    __syncthreads();

    bf16x8 a[4], b[4];
#pragma unroll
    for (int t = 0; t < 4; t++) {
      a[t] = *(const bf16x8*)&As[(wr * 64 + t * 16 + fr) * 32 + fhi * 8];
      b[t] = *(const bf16x8*)&Bs[(wc * 64 + t * 16 + fr) * 32 + fhi * 8];
    }
#pragma unroll
    for (int mt = 0; mt < 4; mt++)
#pragma unroll
      for (int nt = 0; nt < 4; nt++)
        acc[mt][nt] = __builtin_amdgcn_mfma_f32_16x16x32_bf16(a[mt], b[nt], acc[mt][nt], 0, 0, 0);
    __syncthreads();
  }

#pragma unroll
  for (int mt = 0; mt < 4; mt++) {
#pragma unroll
    for (int nt = 0; nt < 4; nt++) {
      const int col = n0 + wc * 64 + nt * 16 + fr;
      const float bv = bias[col];
#pragma unroll
      for (int r = 0; r < 4; r++) {
        const int row = m0 + wr * 64 + mt * 16 + fhi * 4 + r;
        const float v = acc[mt][nt][r] + bv;
        const int b = row >> 9, s = row & 511;
        if (col < 1024) {
          const int h = col >> 6, d = col & 63;
          Kout[(((size_t)(b * 16 + h)) * 512 + s) * 64 + d] = f2bf(v);
        } else {
          const int c2 = col - 1024;
          const int h = c2 >> 6, d = c2 & 63;
          VTout[(((size_t)(b * 16 + h)) * 64 + d) * 512 + s] = f2bf(v);
        }
      }
    }
  }
}

// ---------------- 256-tile 8-phase bf16 GEMM (T2+T3+T4+T5) ----------------

template<int MODE>
__launch_bounds__(512, 1)
__global__ void gemm256(const u16* __restrict__ A, const u16* __restrict__ BT,
                        const float* __restrict__ bias, void* __restrict__ C0,
                        int M, int N, int K) {
  __shared__ __align__(16) u16 As[2][16384];
  __shared__ __align__(16) u16 Bs[2][16384];
  const int tid = threadIdx.x;
  const int w = tid >> 6, l = tid & 63;
  const int wm = w >> 2, wn = w & 3;
  const int fr = l & 15, fhi = l >> 4;

  const int nblk = gridDim.x;
  const int nN = N >> 8;
  const int o = blockIdx.x;
  const int tIdx = (o & 7) * (nblk >> 3) + (o >> 3);
  const int m0 = (tIdx / nN) << 8;
  const int n0 = (tIdx % nN) << 8;

  const int rowoff = tid >> 3;
  const int gchunk = (tid & 7) ^ (rowoff & 7);
  const u16* Abase = A + (size_t)(m0 + rowoff) * K + gchunk * 8;
  const u16* Bbase = BT + (size_t)(n0 + rowoff) * K + gchunk * 8;
  const int ldsoff = w * 512;

  const f32x4 fz = {0.f, 0.f, 0.f, 0.f};
  f32x4 acc[2][4][4];
#pragma unroll
  for (int mh = 0; mh < 2; mh++)
#pragma unroll
    for (int m = 0; m < 4; m++)
#pragma unroll
      for (int n = 0; n < 4; n++) acc[mh][m][n] = fz;

  const int KT = K >> 6;

#pragma unroll
  for (int p = 0; p < 4; ++p) {
    gload_lds16(Abase + (size_t)(p * 64) * K, &As[0][p * 4096 + ldsoff]);
    gload_lds16(Bbase + (size_t)(p * 64) * K, &Bs[0][p * 4096 + ldsoff]);
  }
  asm volatile("s_waitcnt vmcnt(0)" ::: "memory");
  __builtin_amdgcn_s_barrier();

  int nb = 0;
  for (int kt = 0; kt < KT; ++kt) {
    const int knext = (kt + 1) << 6;
    const bool more = (kt + 1) < KT;
#pragma unroll
    for (int p = 0; p < 4; ++p) {
      const int mh = p >> 1, kk = p & 1;
      const int ch = ((kk << 2) | fhi) ^ (fr & 7);
      bf16x8 af[4], bfr[4];
#pragma unroll
      for (int m = 0; m < 4; ++m) {
        const int row = wm * 128 + mh * 64 + m * 16 + fr;
        af[m] = *(const bf16x8*)((const char*)&As[nb][0] + row * 128 + ch * 16);
      }
#pragma unroll
      for (int n = 0; n < 4; ++n) {
        const int row = wn * 64 + n * 16 + fr;
        bfr[n] = *(const bf16x8*)((const char*)&Bs[nb][0] + row * 128 + ch * 16);
      }
      if (more) {
        gload_lds16(Abase + (size_t)(p * 64) * K + knext, &As[nb ^ 1][p * 4096 + ldsoff]);
        gload_lds16(Bbase + (size_t)(p * 64) * K + knext, &Bs[nb ^ 1][p * 4096 + ldsoff]);
      }
      __builtin_amdgcn_s_barrier();
      asm volatile("s_waitcnt lgkmcnt(0)" ::: "memory");
      __builtin_amdgcn_s_setprio(1);
#pragma unroll
      for (int m = 0; m < 4; ++m)
#pragma unroll
        for (int n = 0; n < 4; ++n)
          acc[mh][m][n] = __builtin_amdgcn_mfma_f32_16x16x32_bf16(af[m], bfr[n], acc[mh][m][n], 0, 0, 0);
      __builtin_amdgcn_s_setprio(0);
      __builtin_amdgcn_s_barrier();
    }
    asm volatile("s_waitcnt vmcnt(0)" ::: "memory");
    __builtin_amdgcn_s_barrier();
    nb ^= 1;
  }

#pragma unroll
  for (int mh = 0; mh < 2; ++mh)
#pragma unroll
    for (int m = 0; m < 4; ++m)
#pragma unroll
      for (int n = 0; n < 4; ++n) {
        const int col = n0 + wn * 64 + n * 16 + fr;
        const float bv = bias[col];
#pragma unroll
        for (int r = 0; r < 4; ++r) {
          const int row = m0 + wm * 128 + mh * 64 + m * 16 + fhi * 4 + r;
          const float v = acc[mh][m][n][r] + bv;
          if (MODE == 0)
            ((u16*)C0)[(size_t)row * N + col] = f2bf(v * 0.125f);
          else
            ((float*)C0)[(size_t)row * N + col] = v;
        }
      }
}

// ---------------- fused attention v10: 16 q-rows/wave, 4 blocks/CU ----------------
// r8's verified schedule with the wave tile HALVED (no mt dimension) so the
// true register footprint (~70-100) fits 4 waves/SIMD without spill (r9's
// failure mode). Grid doubles to 4096 blocks (64 q-rows per block).
// K staged via double-buffered LDS global_load_lds (both-sides XOR swizzle);
// V direct from L2 (first half after QK, second between PV halves);
// no-max softmax; wave-private swizzled P (2KB/wave).
__launch_bounds__(256, 4)
__global__ void attn_kernel(const u16* __restrict__ Q, const u16* __restrict__ Kb,
                            const u16* __restrict__ VT, const float* __restrict__ maskf,
                            u16* __restrict__ O) {
  __shared__ __align__(16) u16 Ks[2][4096];  // 2 x 8KB K tiles (64 s x 64 d)
  __shared__ __align__(16) u16 Ps[4][1024];  // 2KB per wave, swizzled P[16][64]
  const int tid = threadIdx.x, w = tid >> 6, l = tid & 63;
  const int fr = l & 15, fhi = l >> 4;

  // XCD-aware decode: 4096 blocks, 512/XCD -> 8 contiguous bh per XCD
  const int rid = blockIdx.x;
  const int orig = ((rid & 7) << 9) + (rid >> 3);
  const int bh = orig >> 6, qb = orig & 63;
  const int b = bh >> 4, h = bh & 15;
  const int rowbase = b * NQ + qb * 64 + w * 16;

  // Q fragments in registers (B-operand of swapped QK^T): 16 q-rows
  bf16x8 qf[2];
#pragma unroll
  for (int kk = 0; kk < 2; kk++)
    qf[kk] = *(const bf16x8*)&Q[(size_t)(rowbase + fr) * DIMC +
                                h * 64 + kk * 32 + fhi * 8];

  const u16* Kg = Kb + (size_t)bh * NS * HDIM;   // [512][64]
  const u16* Vg = VT + (size_t)bh * HDIM * NS;   // [64][512]
  const float* mrow = maskf + b * NS;

  // K staging: wave w covers rows w*16..w*16+15 (2 instrs of 8 rows).
  const int srow = l >> 3;
  const int schunk = (l & 7) ^ (srow & 7);
  const u16* Kst = Kg + (size_t)(w * 16 + srow) * HDIM + schunk * 8;

  const f32x4 fz = {0.f, 0.f, 0.f, 0.f};
  float l_run = 0.f;
  f32x4 o_acc[4];
#pragma unroll
  for (int dn = 0; dn < 4; dn++) o_acc[dn] = fz;

  u16* Pw = Ps[w];

  // prologue: stage K tile 0
  gload_lds16(Kst, &Ks[0][w * 1024]);
  gload_lds16(Kst + 8 * HDIM, &Ks[0][w * 1024 + 512]);
  __syncthreads();

#pragma unroll
  for (int t = 0; t < 8; ++t) {
    const int sc = t * 64;
    const int cb = t & 1;

    // issue next tile's K stage (waited by the barrier at iteration end)
    {
      const int scn = ((t + 1) & 7) * 64;
      gload_lds16(Kst + (size_t)scn * HDIM, &Ks[cb ^ 1][w * 1024]);
      gload_lds16(Kst + (size_t)(scn + 8) * HDIM, &Ks[cb ^ 1][w * 1024 + 512]);
    }

    // S^T = K Q^T : lane holds S^T[s = sn*16+fhi*4+r][q = fr]
    f32x4 sacc[4];
#pragma unroll
    for (int sn = 0; sn < 4; sn++) sacc[sn] = fz;

    __builtin_amdgcn_s_setprio(1);
#pragma unroll
    for (int kk = 0; kk < 2; kk++) {
      bf16x8 kf[4];
#pragma unroll
      for (int sn = 0; sn < 4; sn++) {
        const int byte = (sn * 16 + fr) * 128 + ((((kk << 2) | fhi) ^ (fr & 7)) << 4);
        kf[sn] = *(const bf16x8*)((const char*)&Ks[cb][0] + byte);
      }
#pragma unroll
      for (int sn = 0; sn < 4; sn++)
        sacc[sn] = __builtin_amdgcn_mfma_f32_16x16x32_bf16(kf[sn], qf[kk], sacc[sn], 0, 0, 0);
    }
    __builtin_amdgcn_s_setprio(0);

    // V first half issued here: softmax covers its L2 latency.
    bf16x8 vf0[4];
#pragma unroll
    for (int dn = 0; dn < 4; dn++)
      vf0[dn] = *(const bf16x8*)&Vg[(size_t)(dn * 16 + fr) * NS + sc + fhi * 8];

    // mask values: s = sc + sn*16 + fhi*4 + r
    float4 mv4[4];
#pragma unroll
    for (int sn = 0; sn < 4; sn++)
      mv4[sn] = *(const float4*)&mrow[sc + sn * 16 + fhi * 4];

    // no-max softmax: e = 2^(s*log2e + mask); per-lane partial sums only
    {
      float ls = 0.f;
      const int qrow = fr;
#pragma unroll
      for (int sn = 0; sn < 4; sn++) {
        const float e0 = EXP2F(fmaf(sacc[sn][0], LOG2E, ((const float*)&mv4[sn])[0]));
        const float e1 = EXP2F(fmaf(sacc[sn][1], LOG2E, ((const float*)&mv4[sn])[1]));
        const float e2 = EXP2F(fmaf(sacc[sn][2], LOG2E, ((const float*)&mv4[sn])[2]));
        const float e3 = EXP2F(fmaf(sacc[sn][3], LOG2E, ((const float*)&mv4[sn])[3]));
        ls += (e0 + e1) + (e2 + e3);
        int byte = qrow * 128 + sn * 32 + fhi * 8;
        byte ^= (qrow & 7) << 4;
        uint2 pk;
        pk.x = pack_bf2(e0, e1);
        pk.y = pack_bf2(e2, e3);
        *(uint2*)((char*)Pw + byte) = pk;
      }
      l_run += ls;
    }
    asm volatile("s_waitcnt lgkmcnt(0)" ::: "memory");

    // O += P V, split in K halves so only one V half is live at a time.
    __builtin_amdgcn_s_setprio(1);
    {
      int byte0 = fr * 128 + fhi * 16;
      byte0 ^= (fr & 7) << 4;
      const bf16x8 pa0 = *(const bf16x8*)((char*)Pw + byte0);
#pragma unroll
      for (int dn = 0; dn < 4; dn++)
        o_acc[dn] = __builtin_amdgcn_mfma_f32_16x16x32_bf16(pa0, vf0[dn], o_acc[dn], 0, 0, 0);
    }
    __builtin_amdgcn_s_setprio(0);

    // V second half between PV halves
    bf16x8 vf1[4];
#pragma unroll
    for (int dn = 0; dn < 4; dn++)
      vf1[dn] = *(const bf16x8*)&Vg[(size_t)(dn * 16 + fr) * NS + sc + 32 + fhi * 8];

    __builtin_amdgcn_s_setprio(1);
    {
      int byte1 = fr * 128 + 64 + fhi * 16;
      byte1 ^= (fr & 7) << 4;
      const bf16x8 pa1 = *(const bf16x8*)((char*)Pw + byte1);
#pragma unroll
      for (int dn = 0; dn < 4; dn++)
        o_acc[dn] = __builtin_amdgcn_mfma_f32_16x16x32_bf16(pa1, vf1[dn], o_acc[dn], 0, 0, 0);
    }
    __builtin_amdgcn_s_setprio(0);

    // next K tile staged + everyone done with Ks[cb]
    __syncthreads();
  }

  // epilogue: reduce l across the 4 fhi groups (once), normalize, store
  l_run += __shfl_xor(l_run, 16);
  l_run += __shfl_xor(l_run, 32);
  float lo[4];
#pragma unroll
  for (int r = 0; r < 4; r++) {
    lo[r] = RCPF(__shfl(l_run, fhi * 4 + r));
  }
#pragma unroll
  for (int dn = 0; dn < 4; dn++)
#pragma unroll
    for (int r = 0; r < 4; r++) {
      const float v = o_acc[dn][r] * lo[r];
      const int row = rowbase + fhi * 4 + r;
      O[(size_t)row * DIMC + h * 64 + dn * 16 + fr] = f2bf(v);
    }
}

// ---------------- launch ----------------

extern "C" void kernel_launch(void* const* d_in, const int* in_sizes, int n_in,
                              void* d_out, int out_size, void* d_ws, size_t ws_size,
                              hipStream_t stream) {
  const float* x      = (const float*)d_in[0];
  const float* ctx    = (const float*)d_in[1];
  const int*   cmask  = (const int*)d_in[2];
  const float* q_w    = (const float*)d_in[3];
  const float* q_b    = (const float*)d_in[4];
  const float* kv_w   = (const float*)d_in[5];
  const float* kv_b   = (const float*)d_in[6];
  const float* proj_w = (const float*)d_in[7];
  const float* proj_b = (const float*)d_in[8];
  float* out = (float*)d_out;

  char* ws = (char*)d_ws;
  size_t off = 0;
  auto alloc = [&](size_t bytes) {
    void* p = ws + off;
    off += (bytes + 255) & ~(size_t)255;
    return p;
  };
  u16* x_bf   = (u16*)alloc((size_t)16384 * 1024 * 2);
  u16* ctx_bf = (u16*)alloc((size_t)2048 * 1024 * 2);
  u16* qwT    = (u16*)alloc((size_t)1024 * 1024 * 2);
  u16* kvwT   = (u16*)alloc((size_t)2048 * 1024 * 2);
  u16* pwT    = (u16*)alloc((size_t)1024 * 1024 * 2);
  u16* Qb     = (u16*)alloc((size_t)16384 * 1024 * 2);
  u16* Kbuf   = (u16*)alloc((size_t)64 * 512 * 64 * 2);
  u16* VTbuf  = (u16*)alloc((size_t)64 * 64 * 512 * 2);
  u16* Ob     = (u16*)alloc((size_t)16384 * 1024 * 2);
  float* maskf = (float*)alloc((size_t)NB * NS * 4);

  // all preprocessing in one launch
  prep_kernel<<<6664, 256, 0, stream>>>(x, ctx, cmask, q_w, kv_w, proj_w,
                                        x_bf, ctx_bf, qwT, kvwT, pwT, maskf);

  // Q = (x @ q_w + q_b) * 0.125  (bf16 out, attention scale folded) -- 8-phase 256^2
  gemm256<0><<<256, 512, 0, stream>>>(x_bf, qwT, q_b, Qb, 16384, 1024, 1024);
  // KV = ctx @ kv_w + kv_b  (scatter to K / V^T) -- 128^2
  gemm_kv<<<dim3(16, 16), 256, 0, stream>>>(ctx_bf, kvwT, kv_b, Kbuf, VTbuf, 2048, 2048, 1024);
  // attention (16 q-rows/wave, 4096 blocks)
  attn_kernel<<<4096, 256, 0, stream>>>(Qb, Kbuf, VTbuf, maskf, Ob);
  // out = O @ proj_w + proj_b (f32) -- 8-phase 256^2
  gemm256<2><<<256, 512, 0, stream>>>(Ob, pwT, proj_b, out, 16384, 1024, 1024);
}

// Round 11
// 212.420 us; speedup vs baseline: 1.3072x; 1.3072x over previous
//
#include <hip/hip_runtime.h>
#include <hip/hip_bf16.h>

typedef __attribute__((ext_vector_type(8))) short bf16x8;
typedef __attribute__((ext_vector_type(4))) float f32x4;
typedef unsigned short u16;

#define DIMC 1024
#define NHEAD 16
#define HDIM 64
#define NB 4
#define NQ 4096
#define NS 512

#define LOG2E 1.44269504f

#if __has_builtin(__builtin_amdgcn_exp2f)
#define EXP2F(x) __builtin_amdgcn_exp2f(x)
#else
#define EXP2F(x) __expf(0.69314718f * (x))
#endif

#if __has_builtin(__builtin_amdgcn_rcpf)
#define RCPF(x) __builtin_amdgcn_rcpf(x)
#else
#define RCPF(x) (1.0f / (x))
#endif

__device__ __forceinline__ u16 f2bf(float f) {
  __hip_bfloat16 h = __float2bfloat16(f);
  return *reinterpret_cast<u16*>(&h);
}

__device__ __forceinline__ unsigned pack_bf2(float a, float b) {
  __hip_bfloat162 h2 = __float22bfloat162_rn(make_float2(a, b));
  return *reinterpret_cast<unsigned*>(&h2);
}

__device__ __forceinline__ void gload_lds16(const void* g, void* s) {
  __builtin_amdgcn_global_load_lds(
      (const __attribute__((address_space(1))) void*)g,
      (__attribute__((address_space(3))) void*)s, 16, 0, 0);
}

// ---------------- fused preprocessing kernel ----------------

__device__ __forceinline__ void cvt_body(const float* __restrict__ in,
                                         u16* __restrict__ out, int base, int nblk,
                                         int n4) {
  const int stride = nblk * 256;
  for (int i = base * 256 + threadIdx.x; i < n4; i += stride) {
    float4 v = *(const float4*)(in + (size_t)i * 4);
    ushort4 o;
    o.x = f2bf(v.x); o.y = f2bf(v.y); o.z = f2bf(v.z); o.w = f2bf(v.w);
    *(ushort4*)(out + (size_t)i * 4) = o;
  }
}

__global__ void prep_kernel(const float* __restrict__ x, const float* __restrict__ ctx,
                            const int* __restrict__ cmask,
                            const float* __restrict__ q_w, const float* __restrict__ kv_w,
                            const float* __restrict__ proj_w,
                            u16* __restrict__ x_bf, u16* __restrict__ ctx_bf,
                            u16* __restrict__ qwT, u16* __restrict__ kvwT,
                            u16* __restrict__ pwT, float* __restrict__ maskf) {
  __shared__ float t[32][33];
  const int bid = blockIdx.x;
  if (bid < 2048) {
    cvt_body(x, x_bf, bid, 2048, 16777216 / 4);
    return;
  }
  if (bid < 2560) {
    cvt_body(ctx, ctx_bf, bid - 2048, 512, 2097152 / 4);
    return;
  }
  if (bid >= 6656) {
    const int i = (bid - 6656) * 256 + threadIdx.x;
    if (i < NB * NS) maskf[i] = cmask[i] ? -1e30f : 0.0f;
    return;
  }
  // transpose jobs: W [K][N] f32 -> WT [N][K] bf16
  const float* W;
  u16* WT;
  int K, N, local;
  if (bid < 3584) {
    W = q_w; WT = qwT; K = 1024; N = 1024; local = bid - 2560;
  } else if (bid < 5632) {
    W = kv_w; WT = kvwT; K = 1024; N = 2048; local = bid - 3584;
  } else {
    W = proj_w; WT = pwT; K = 1024; N = 1024; local = bid - 5632;
  }
  const int nbx = N >> 5;
  const int bx = (local % nbx) * 32;
  const int by = (local / nbx) * 32;
  const int tx = threadIdx.x & 31, ty = threadIdx.x >> 5;  // ty 0..7
#pragma unroll
  for (int i = 0; i < 32; i += 8)
    t[ty + i][tx] = W[(size_t)(by + ty + i) * N + bx + tx];
  __syncthreads();
#pragma unroll
  for (int i = 0; i < 32; i += 8)
    WT[(size_t)(bx + ty + i) * K + by + tx] = f2bf(t[tx][ty + i]);
}

// ---------------- 128-tile bf16 GEMM (KV scatter only) ----------------

__launch_bounds__(256)
__global__ void gemm_kv(const u16* __restrict__ A, const u16* __restrict__ BT,
                        const float* __restrict__ bias, u16* __restrict__ Kout,
                        u16* __restrict__ VTout, int M, int N, int K) {
  __shared__ __align__(16) u16 As[128 * 32];
  __shared__ __align__(16) u16 Bs[128 * 32];
  const int tid = threadIdx.x;
  const int w = tid >> 6, l = tid & 63;
  const int wr = w >> 1, wc = w & 1;
  const int fr = l & 15, fhi = l >> 4;

  const int nwg = gridDim.x * gridDim.y;
  const int o = blockIdx.y * gridDim.x + blockIdx.x;
  const int tIdx = (o & 7) * (nwg >> 3) + (o >> 3);
  const int m0 = (tIdx / gridDim.x) * 128;
  const int n0 = (tIdx % gridDim.x) * 128;

  const f32x4 fz = {0.f, 0.f, 0.f, 0.f};
  f32x4 acc[4][4];
#pragma unroll
  for (int mt = 0; mt < 4; mt++)
#pragma unroll
    for (int nt = 0; nt < 4; nt++) acc[mt][nt] = fz;

  const int f0 = w * 2048 + l * 16;
  const int f1 = f0 + 1024;
  const int ar0 = f0 >> 6, ac0 = (f0 & 63) >> 1;
  const int ar1 = f1 >> 6, ac1 = (f1 & 63) >> 1;
  const u16* Ag0 = A + (size_t)(m0 + ar0) * K + ac0;
  const u16* Ag1 = A + (size_t)(m0 + ar1) * K + ac1;
  const u16* Bg0 = BT + (size_t)(n0 + ar0) * K + ac0;
  const u16* Bg1 = BT + (size_t)(n0 + ar1) * K + ac1;

  for (int k0 = 0; k0 < K; k0 += 32) {
    gload_lds16(Ag0 + k0, &As[w * 1024]);
    gload_lds16(Ag1 + k0, &As[w * 1024 + 512]);
    gload_lds16(Bg0 + k0, &Bs[w * 1024]);
    gload_lds16(Bg1 + k0, &Bs[w * 1024 + 512]);
    __syncthreads();

    bf16x8 a[4], b[4];
#pragma unroll
    for (int t = 0; t < 4; t++) {
      a[t] = *(const bf16x8*)&As[(wr * 64 + t * 16 + fr) * 32 + fhi * 8];
      b[t] = *(const bf16x8*)&Bs[(wc * 64 + t * 16 + fr) * 32 + fhi * 8];
    }
#pragma unroll
    for (int mt = 0; mt < 4; mt++)
#pragma unroll
      for (int nt = 0; nt < 4; nt++)
        acc[mt][nt] = __builtin_amdgcn_mfma_f32_16x16x32_bf16(a[mt], b[nt], acc[mt][nt], 0, 0, 0);
    __syncthreads();
  }

#pragma unroll
  for (int mt = 0; mt < 4; mt++) {
#pragma unroll
    for (int nt = 0; nt < 4; nt++) {
      const int col = n0 + wc * 64 + nt * 16 + fr;
      const float bv = bias[col];
#pragma unroll
      for (int r = 0; r < 4; r++) {
        const int row = m0 + wr * 64 + mt * 16 + fhi * 4 + r;
        const float v = acc[mt][nt][r] + bv;
        const int b = row >> 9, s = row & 511;
        if (col < 1024) {
          const int h = col >> 6, d = col & 63;
          Kout[(((size_t)(b * 16 + h)) * 512 + s) * 64 + d] = f2bf(v);
        } else {
          const int c2 = col - 1024;
          const int h = c2 >> 6, d = c2 & 63;
          VTout[(((size_t)(b * 16 + h)) * 64 + d) * 512 + s] = f2bf(v);
        }
      }
    }
  }
}

// ---------------- 256-tile 8-phase bf16 GEMM (T2+T3+T4+T5) ----------------

template<int MODE>
__launch_bounds__(512, 1)
__global__ void gemm256(const u16* __restrict__ A, const u16* __restrict__ BT,
                        const float* __restrict__ bias, void* __restrict__ C0,
                        int M, int N, int K) {
  __shared__ __align__(16) u16 As[2][16384];
  __shared__ __align__(16) u16 Bs[2][16384];
  const int tid = threadIdx.x;
  const int w = tid >> 6, l = tid & 63;
  const int wm = w >> 2, wn = w & 3;
  const int fr = l & 15, fhi = l >> 4;

  const int nblk = gridDim.x;
  const int nN = N >> 8;
  const int o = blockIdx.x;
  const int tIdx = (o & 7) * (nblk >> 3) + (o >> 3);
  const int m0 = (tIdx / nN) << 8;
  const int n0 = (tIdx % nN) << 8;

  const int rowoff = tid >> 3;
  const int gchunk = (tid & 7) ^ (rowoff & 7);
  const u16* Abase = A + (size_t)(m0 + rowoff) * K + gchunk * 8;
  const u16* Bbase = BT + (size_t)(n0 + rowoff) * K + gchunk * 8;
  const int ldsoff = w * 512;

  const f32x4 fz = {0.f, 0.f, 0.f, 0.f};
  f32x4 acc[2][4][4];
#pragma unroll
  for (int mh = 0; mh < 2; mh++)
#pragma unroll
    for (int m = 0; m < 4; m++)
#pragma unroll
      for (int n = 0; n < 4; n++) acc[mh][m][n] = fz;

  const int KT = K >> 6;

#pragma unroll
  for (int p = 0; p < 4; ++p) {
    gload_lds16(Abase + (size_t)(p * 64) * K, &As[0][p * 4096 + ldsoff]);
    gload_lds16(Bbase + (size_t)(p * 64) * K, &Bs[0][p * 4096 + ldsoff]);
  }
  asm volatile("s_waitcnt vmcnt(0)" ::: "memory");
  __builtin_amdgcn_s_barrier();

  int nb = 0;
  for (int kt = 0; kt < KT; ++kt) {
    const int knext = (kt + 1) << 6;
    const bool more = (kt + 1) < KT;
#pragma unroll
    for (int p = 0; p < 4; ++p) {
      const int mh = p >> 1, kk = p & 1;
      const int ch = ((kk << 2) | fhi) ^ (fr & 7);
      bf16x8 af[4], bfr[4];
#pragma unroll
      for (int m = 0; m < 4; ++m) {
        const int row = wm * 128 + mh * 64 + m * 16 + fr;
        af[m] = *(const bf16x8*)((const char*)&As[nb][0] + row * 128 + ch * 16);
      }
#pragma unroll
      for (int n = 0; n < 4; ++n) {
        const int row = wn * 64 + n * 16 + fr;
        bfr[n] = *(const bf16x8*)((const char*)&Bs[nb][0] + row * 128 + ch * 16);
      }
      if (more) {
        gload_lds16(Abase + (size_t)(p * 64) * K + knext, &As[nb ^ 1][p * 4096 + ldsoff]);
        gload_lds16(Bbase + (size_t)(p * 64) * K + knext, &Bs[nb ^ 1][p * 4096 + ldsoff]);
      }
      __builtin_amdgcn_s_barrier();
      asm volatile("s_waitcnt lgkmcnt(0)" ::: "memory");
      __builtin_amdgcn_s_setprio(1);
#pragma unroll
      for (int m = 0; m < 4; ++m)
#pragma unroll
        for (int n = 0; n < 4; ++n)
          acc[mh][m][n] = __builtin_amdgcn_mfma_f32_16x16x32_bf16(af[m], bfr[n], acc[mh][m][n], 0, 0, 0);
      __builtin_amdgcn_s_setprio(0);
      __builtin_amdgcn_s_barrier();
    }
    asm volatile("s_waitcnt vmcnt(0)" ::: "memory");
    __builtin_amdgcn_s_barrier();
    nb ^= 1;
  }

#pragma unroll
  for (int mh = 0; mh < 2; ++mh)
#pragma unroll
    for (int m = 0; m < 4; ++m)
#pragma unroll
      for (int n = 0; n < 4; ++n) {
        const int col = n0 + wn * 64 + n * 16 + fr;
        const float bv = bias[col];
#pragma unroll
        for (int r = 0; r < 4; ++r) {
          const int row = m0 + wm * 128 + mh * 64 + m * 16 + fhi * 4 + r;
          const float v = acc[mh][m][n][r] + bv;
          if (MODE == 0)
            ((u16*)C0)[(size_t)row * N + col] = f2bf(v * 0.125f);
          else
            ((float*)C0)[(size_t)row * N + col] = v;
        }
      }
}

// ---------------- fused attention v11: K fully LDS-resident, barrier-free loop --
// 512 blocks = 64 bh x 8 q-chunks (XCD-grouped). Prologue stages the WHOLE
// K [512][64] (64KB) into swizzled LDS once (vmcnt(0) + one barrier). Main
// loop (4 q-tiles x 8 s-tiles per wave, r8's exact 32-q-row math) has ZERO
// barriers and ZERO staging: K ds_reads hit resident LDS (fr&7 XOR involution,
// stage key r&7 == read key), P wave-private swizzled, V direct from L2.
// LDS 80KB -> 2 blocks/CU = 8 waves/CU free-running.
__launch_bounds__(256, 2)
__global__ void attn_kernel(const u16* __restrict__ Q, const u16* __restrict__ Kb,
                            const u16* __restrict__ VT, const float* __restrict__ maskf,
                            u16* __restrict__ O) {
  __shared__ __align__(16) u16 Ks[512 * 64];  // 64KB swizzled K
  __shared__ __align__(16) u16 Ps[4][2048];   // 4KB per wave, swizzled P[32][64]
  const int tid = threadIdx.x, w = tid >> 6, l = tid & 63;
  const int fr = l & 15, fhi = l >> 4;

  // XCD-aware decode: 512 blocks, 64/XCD -> 8 contiguous bh per XCD
  const int rid = blockIdx.x;
  const int orig = ((rid & 7) << 6) + (rid >> 3);
  const int bh = orig >> 3, qc = orig & 7;
  const int b = bh >> 4, h = bh & 15;

  const u16* Kg = Kb + (size_t)bh * NS * HDIM;   // [512][64]
  const u16* Vg = VT + (size_t)bh * HDIM * NS;   // [64][512]
  const float* mrow = maskf + b * NS;

  // ---- prologue: stage ALL of K into swizzled LDS (once) ----
  // iteration it: rows it*32 + w*8 + (l>>3), chunk (l&7)^(row&7); linear LDS
  // dest = it*4096B + w*1024B + l*16B  (wave-uniform base + lane*16).
  {
    const int r0 = w * 8 + (l >> 3);
#pragma unroll
    for (int it = 0; it < 16; ++it) {
      const int r = it * 32 + r0;
      const int c = (l & 7) ^ (r & 7);
      gload_lds16(Kg + (size_t)r * HDIM + c * 8, &Ks[it * 2048 + w * 512]);
    }
  }
  asm volatile("s_waitcnt vmcnt(0)" ::: "memory");
  __syncthreads();
  // ---- K resident; no barriers from here on ----

  u16* Pw = Ps[w];
  const f32x4 fz = {0.f, 0.f, 0.f, 0.f};

#pragma unroll 1
  for (int qt = 0; qt < 4; ++qt) {
    const int rowbase = b * NQ + qc * 512 + w * 128 + qt * 32;

    // Q fragments (B-operand of swapped QK^T)
    bf16x8 qf[2][2];
#pragma unroll
    for (int mt = 0; mt < 2; mt++)
#pragma unroll
      for (int kk = 0; kk < 2; kk++)
        qf[mt][kk] = *(const bf16x8*)&Q[(size_t)(rowbase + mt * 16 + fr) * DIMC +
                                        h * 64 + kk * 32 + fhi * 8];

    float l_run[2] = {0.f, 0.f};
    f32x4 o_acc[2][4];
#pragma unroll
    for (int mt = 0; mt < 2; mt++)
#pragma unroll
      for (int dn = 0; dn < 4; dn++) o_acc[mt][dn] = fz;

#pragma unroll
    for (int t = 0; t < 8; ++t) {
      const int sc = t * 64;

      // S^T = K Q^T : lane holds S^T[s = sc+sn*16+fhi*4+r][q = mt*16+fr]
      f32x4 sacc[2][4];
#pragma unroll
      for (int mt = 0; mt < 2; mt++)
#pragma unroll
        for (int sn = 0; sn < 4; sn++) sacc[mt][sn] = fz;

      __builtin_amdgcn_s_setprio(1);
#pragma unroll
      for (int kk = 0; kk < 2; kk++) {
        bf16x8 kf[4];
#pragma unroll
        for (int sn = 0; sn < 4; sn++) {
          const int row = sc + sn * 16 + fr;
          const int byte = row * 128 + ((((kk << 2) | fhi) ^ (fr & 7)) << 4);
          kf[sn] = *(const bf16x8*)((const char*)&Ks[0] + byte);
        }
#pragma unroll
        for (int sn = 0; sn < 4; sn++)
#pragma unroll
          for (int mt = 0; mt < 2; mt++)
            sacc[mt][sn] = __builtin_amdgcn_mfma_f32_16x16x32_bf16(kf[sn], qf[mt][kk], sacc[mt][sn], 0, 0, 0);
      }
      __builtin_amdgcn_s_setprio(0);

      // V first half: softmax covers its L2 latency.
      bf16x8 vf0[4];
#pragma unroll
      for (int dn = 0; dn < 4; dn++)
        vf0[dn] = *(const bf16x8*)&Vg[(size_t)(dn * 16 + fr) * NS + sc + fhi * 8];

      float4 mv4[4];
#pragma unroll
      for (int sn = 0; sn < 4; sn++)
        mv4[sn] = *(const float4*)&mrow[sc + sn * 16 + fhi * 4];

      // no-max softmax: e = 2^(s*log2e + mask); per-lane partial sums only
#pragma unroll
      for (int mt = 0; mt < 2; mt++) {
        float ls = 0.f;
        const int qrow = mt * 16 + fr;
#pragma unroll
        for (int sn = 0; sn < 4; sn++) {
          const float e0 = EXP2F(fmaf(sacc[mt][sn][0], LOG2E, ((const float*)&mv4[sn])[0]));
          const float e1 = EXP2F(fmaf(sacc[mt][sn][1], LOG2E, ((const float*)&mv4[sn])[1]));
          const float e2 = EXP2F(fmaf(sacc[mt][sn][2], LOG2E, ((const float*)&mv4[sn])[2]));
          const float e3 = EXP2F(fmaf(sacc[mt][sn][3], LOG2E, ((const float*)&mv4[sn])[3]));
          ls += (e0 + e1) + (e2 + e3);
          int byte = qrow * 128 + sn * 32 + fhi * 8;
          byte ^= (qrow & 7) << 4;
          uint2 pk;
          pk.x = pack_bf2(e0, e1);
          pk.y = pack_bf2(e2, e3);
          *(uint2*)((char*)Pw + byte) = pk;
        }
        l_run[mt] += ls;
      }
      asm volatile("s_waitcnt lgkmcnt(0)" ::: "memory");

      // O += P V, split in K halves so only one V half is live at a time.
      __builtin_amdgcn_s_setprio(1);
#pragma unroll
      for (int mt = 0; mt < 2; mt++) {
        int byte0 = (mt * 16 + fr) * 128 + fhi * 16;
        byte0 ^= (fr & 7) << 4;
        const bf16x8 pa0 = *(const bf16x8*)((char*)Pw + byte0);
#pragma unroll
        for (int dn = 0; dn < 4; dn++)
          o_acc[mt][dn] = __builtin_amdgcn_mfma_f32_16x16x32_bf16(pa0, vf0[dn], o_acc[mt][dn], 0, 0, 0);
      }
      __builtin_amdgcn_s_setprio(0);

      bf16x8 vf1[4];
#pragma unroll
      for (int dn = 0; dn < 4; dn++)
        vf1[dn] = *(const bf16x8*)&Vg[(size_t)(dn * 16 + fr) * NS + sc + 32 + fhi * 8];

      __builtin_amdgcn_s_setprio(1);
#pragma unroll
      for (int mt = 0; mt < 2; mt++) {
        int byte1 = (mt * 16 + fr) * 128 + 64 + fhi * 16;
        byte1 ^= (fr & 7) << 4;
        const bf16x8 pa1 = *(const bf16x8*)((char*)Pw + byte1);
#pragma unroll
        for (int dn = 0; dn < 4; dn++)
          o_acc[mt][dn] = __builtin_amdgcn_mfma_f32_16x16x32_bf16(pa1, vf1[dn], o_acc[mt][dn], 0, 0, 0);
      }
      __builtin_amdgcn_s_setprio(0);
    }

    // per-q-tile epilogue: reduce l, normalize, store
#pragma unroll
    for (int mt = 0; mt < 2; mt++) {
      l_run[mt] += __shfl_xor(l_run[mt], 16);
      l_run[mt] += __shfl_xor(l_run[mt], 32);
    }
#pragma unroll
    for (int mt = 0; mt < 2; mt++) {
      float lo[4];
#pragma unroll
      for (int r = 0; r < 4; r++) {
        lo[r] = RCPF(__shfl(l_run[mt], fhi * 4 + r));
      }
#pragma unroll
      for (int dn = 0; dn < 4; dn++)
#pragma unroll
        for (int r = 0; r < 4; r++) {
          const float v = o_acc[mt][dn][r] * lo[r];
          const int row = rowbase + mt * 16 + fhi * 4 + r;
          O[(size_t)row * DIMC + h * 64 + dn * 16 + fr] = f2bf(v);
        }
    }
  }
}

// ---------------- launch ----------------

extern "C" void kernel_launch(void* const* d_in, const int* in_sizes, int n_in,
                              void* d_out, int out_size, void* d_ws, size_t ws_size,
                              hipStream_t stream) {
  const float* x      = (const float*)d_in[0];
  const float* ctx    = (const float*)d_in[1];
  const int*   cmask  = (const int*)d_in[2];
  const float* q_w    = (const float*)d_in[3];
  const float* q_b    = (const float*)d_in[4];
  const float* kv_w   = (const float*)d_in[5];
  const float* kv_b   = (const float*)d_in[6];
  const float* proj_w = (const float*)d_in[7];
  const float* proj_b = (const float*)d_in[8];
  float* out = (float*)d_out;

  char* ws = (char*)d_ws;
  size_t off = 0;
  auto alloc = [&](size_t bytes) {
    void* p = ws + off;
    off += (bytes + 255) & ~(size_t)255;
    return p;
  };
  u16* x_bf   = (u16*)alloc((size_t)16384 * 1024 * 2);
  u16* ctx_bf = (u16*)alloc((size_t)2048 * 1024 * 2);
  u16* qwT    = (u16*)alloc((size_t)1024 * 1024 * 2);
  u16* kvwT   = (u16*)alloc((size_t)2048 * 1024 * 2);
  u16* pwT    = (u16*)alloc((size_t)1024 * 1024 * 2);
  u16* Qb     = (u16*)alloc((size_t)16384 * 1024 * 2);
  u16* Kbuf   = (u16*)alloc((size_t)64 * 512 * 64 * 2);
  u16* VTbuf  = (u16*)alloc((size_t)64 * 64 * 512 * 2);
  u16* Ob     = (u16*)alloc((size_t)16384 * 1024 * 2);
  float* maskf = (float*)alloc((size_t)NB * NS * 4);

  // all preprocessing in one launch
  prep_kernel<<<6664, 256, 0, stream>>>(x, ctx, cmask, q_w, kv_w, proj_w,
                                        x_bf, ctx_bf, qwT, kvwT, pwT, maskf);

  // Q = (x @ q_w + q_b) * 0.125  (bf16 out, attention scale folded) -- 8-phase 256^2
  gemm256<0><<<256, 512, 0, stream>>>(x_bf, qwT, q_b, Qb, 16384, 1024, 1024);
  // KV = ctx @ kv_w + kv_b  (scatter to K / V^T) -- 128^2
  gemm_kv<<<dim3(16, 16), 256, 0, stream>>>(ctx_bf, kvwT, kv_b, Kbuf, VTbuf, 2048, 2048, 1024);
  // attention (K LDS-resident, barrier-free loop)
  attn_kernel<<<512, 256, 0, stream>>>(Qb, Kbuf, VTbuf, maskf, Ob);
  // out = O @ proj_w + proj_b (f32) -- 8-phase 256^2
  gemm256<2><<<256, 512, 0, stream>>>(Ob, pwT, proj_b, out, 16384, 1024, 1024);
}

// Round 12
// 182.506 us; speedup vs baseline: 1.5215x; 1.1639x over previous
//
#include <hip/hip_runtime.h>
#include <hip/hip_bf16.h>

typedef __attribute__((ext_vector_type(8))) short bf16x8;
typedef __attribute__((ext_vector_type(4))) float f32x4;
typedef unsigned short u16;

#define DIMC 1024
#define NHEAD 16
#define HDIM 64
#define NB 4
#define NQ 4096
#define NS 512

#define LOG2E 1.44269504f

#if __has_builtin(__builtin_amdgcn_exp2f)
#define EXP2F(x) __builtin_amdgcn_exp2f(x)
#else
#define EXP2F(x) __expf(0.69314718f * (x))
#endif

#if __has_builtin(__builtin_amdgcn_rcpf)
#define RCPF(x) __builtin_amdgcn_rcpf(x)
#else
#define RCPF(x) (1.0f / (x))
#endif

__device__ __forceinline__ u16 f2bf(float f) {
  __hip_bfloat16 h = __float2bfloat16(f);
  return *reinterpret_cast<u16*>(&h);
}

__device__ __forceinline__ unsigned pack_bf2(float a, float b) {
  __hip_bfloat162 h2 = __float22bfloat162_rn(make_float2(a, b));
  return *reinterpret_cast<unsigned*>(&h2);
}

__device__ __forceinline__ void gload_lds16(const void* g, void* s) {
  __builtin_amdgcn_global_load_lds(
      (const __attribute__((address_space(1))) void*)g,
      (__attribute__((address_space(3))) void*)s, 16, 0, 0);
}

// ---------------- fused preprocessing kernel ----------------

__device__ __forceinline__ void cvt_body(const float* __restrict__ in,
                                         u16* __restrict__ out, int base, int nblk,
                                         int n4) {
  const int stride = nblk * 256;
  for (int i = base * 256 + threadIdx.x; i < n4; i += stride) {
    float4 v = *(const float4*)(in + (size_t)i * 4);
    ushort4 o;
    o.x = f2bf(v.x); o.y = f2bf(v.y); o.z = f2bf(v.z); o.w = f2bf(v.w);
    *(ushort4*)(out + (size_t)i * 4) = o;
  }
}

__global__ void prep_kernel(const float* __restrict__ x, const float* __restrict__ ctx,
                            const int* __restrict__ cmask,
                            const float* __restrict__ q_w, const float* __restrict__ kv_w,
                            const float* __restrict__ proj_w,
                            u16* __restrict__ x_bf, u16* __restrict__ ctx_bf,
                            u16* __restrict__ qwT, u16* __restrict__ kvwT,
                            u16* __restrict__ pwT, float* __restrict__ maskf) {
  __shared__ float t[32][33];
  const int bid = blockIdx.x;
  if (bid < 2048) {
    cvt_body(x, x_bf, bid, 2048, 16777216 / 4);
    return;
  }
  if (bid < 2560) {
    cvt_body(ctx, ctx_bf, bid - 2048, 512, 2097152 / 4);
    return;
  }
  if (bid >= 6656) {
    const int i = (bid - 6656) * 256 + threadIdx.x;
    if (i < NB * NS) maskf[i] = cmask[i] ? -1e30f : 0.0f;
    return;
  }
  // transpose jobs: W [K][N] f32 -> WT [N][K] bf16
  const float* W;
  u16* WT;
  int K, N, local;
  if (bid < 3584) {
    W = q_w; WT = qwT; K = 1024; N = 1024; local = bid - 2560;
  } else if (bid < 5632) {
    W = kv_w; WT = kvwT; K = 1024; N = 2048; local = bid - 3584;
  } else {
    W = proj_w; WT = pwT; K = 1024; N = 1024; local = bid - 5632;
  }
  const int nbx = N >> 5;
  const int bx = (local % nbx) * 32;
  const int by = (local / nbx) * 32;
  const int tx = threadIdx.x & 31, ty = threadIdx.x >> 5;  // ty 0..7
#pragma unroll
  for (int i = 0; i < 32; i += 8)
    t[ty + i][tx] = W[(size_t)(by + ty + i) * N + bx + tx];
  __syncthreads();
#pragma unroll
  for (int i = 0; i < 32; i += 8)
    WT[(size_t)(bx + ty + i) * K + by + tx] = f2bf(t[tx][ty + i]);
}

// ---------------- 128-tile bf16 GEMM (KV scatter only) ----------------

__launch_bounds__(256)
__global__ void gemm_kv(const u16* __restrict__ A, const u16* __restrict__ BT,
                        const float* __restrict__ bias, u16* __restrict__ Kout,
                        u16* __restrict__ VTout, int M, int N, int K) {
  __shared__ __align__(16) u16 As[128 * 32];
  __shared__ __align__(16) u16 Bs[128 * 32];
  const int tid = threadIdx.x;
  const int w = tid >> 6, l = tid & 63;
  const int wr = w >> 1, wc = w & 1;
  const int fr = l & 15, fhi = l >> 4;

  const int nwg = gridDim.x * gridDim.y;
  const int o = blockIdx.y * gridDim.x + blockIdx.x;
  const int tIdx = (o & 7) * (nwg >> 3) + (o >> 3);
  const int m0 = (tIdx / gridDim.x) * 128;
  const int n0 = (tIdx % gridDim.x) * 128;

  const f32x4 fz = {0.f, 0.f, 0.f, 0.f};
  f32x4 acc[4][4];
#pragma unroll
  for (int mt = 0; mt < 4; mt++)
#pragma unroll
    for (int nt = 0; nt < 4; nt++) acc[mt][nt] = fz;

  const int f0 = w * 2048 + l * 16;
  const int f1 = f0 + 1024;
  const int ar0 = f0 >> 6, ac0 = (f0 & 63) >> 1;
  const int ar1 = f1 >> 6, ac1 = (f1 & 63) >> 1;
  const u16* Ag0 = A + (size_t)(m0 + ar0) * K + ac0;
  const u16* Ag1 = A + (size_t)(m0 + ar1) * K + ac1;
  const u16* Bg0 = BT + (size_t)(n0 + ar0) * K + ac0;
  const u16* Bg1 = BT + (size_t)(n0 + ar1) * K + ac1;

  for (int k0 = 0; k0 < K; k0 += 32) {
    gload_lds16(Ag0 + k0, &As[w * 1024]);
    gload_lds16(Ag1 + k0, &As[w * 1024 + 512]);
    gload_lds16(Bg0 + k0, &Bs[w * 1024]);
    gload_lds16(Bg1 + k0, &Bs[w * 1024 + 512]);
    __syncthreads();

    bf16x8 a[4], b[4];
#pragma unroll
    for (int t = 0; t < 4; t++) {
      a[t] = *(const bf16x8*)&As[(wr * 64 + t * 16 + fr) * 32 + fhi * 8];
      b[t] = *(const bf16x8*)&Bs[(wc * 64 + t * 16 + fr) * 32 + fhi * 8];
    }
#pragma unroll
    for (int mt = 0; mt < 4; mt++)
#pragma unroll
      for (int nt = 0; nt < 4; nt++)
        acc[mt][nt] = __builtin_amdgcn_mfma_f32_16x16x32_bf16(a[mt], b[nt], acc[mt][nt], 0, 0, 0);
    __syncthreads();
  }

#pragma unroll
  for (int mt = 0; mt < 4; mt++) {
#pragma unroll
    for (int nt = 0; nt < 4; nt++) {
      const int col = n0 + wc * 64 + nt * 16 + fr;
      const float bv = bias[col];
#pragma unroll
      for (int r = 0; r < 4; r++) {
        const int row = m0 + wr * 64 + mt * 16 + fhi * 4 + r;
        const float v = acc[mt][nt][r] + bv;
        const int b = row >> 9, s = row & 511;
        if (col < 1024) {
          const int h = col >> 6, d = col & 63;
          Kout[(((size_t)(b * 16 + h)) * 512 + s) * 64 + d] = f2bf(v);
        } else {
          const int c2 = col - 1024;
          const int h = c2 >> 6, d = c2 & 63;
          VTout[(((size_t)(b * 16 + h)) * 64 + d) * 512 + s] = f2bf(v);
        }
      }
    }
  }
}

// ---------------- 256-tile 8-phase bf16 GEMM (T2+T3+T4+T5) ----------------

template<int MODE>
__launch_bounds__(512, 1)
__global__ void gemm256(const u16* __restrict__ A, const u16* __restrict__ BT,
                        const float* __restrict__ bias, void* __restrict__ C0,
                        int M, int N, int K) {
  __shared__ __align__(16) u16 As[2][16384];
  __shared__ __align__(16) u16 Bs[2][16384];
  const int tid = threadIdx.x;
  const int w = tid >> 6, l = tid & 63;
  const int wm = w >> 2, wn = w & 3;
  const int fr = l & 15, fhi = l >> 4;

  const int nblk = gridDim.x;
  const int nN = N >> 8;
  const int o = blockIdx.x;
  const int tIdx = (o & 7) * (nblk >> 3) + (o >> 3);
  const int m0 = (tIdx / nN) << 8;
  const int n0 = (tIdx % nN) << 8;

  const int rowoff = tid >> 3;
  const int gchunk = (tid & 7) ^ (rowoff & 7);
  const u16* Abase = A + (size_t)(m0 + rowoff) * K + gchunk * 8;
  const u16* Bbase = BT + (size_t)(n0 + rowoff) * K + gchunk * 8;
  const int ldsoff = w * 512;

  const f32x4 fz = {0.f, 0.f, 0.f, 0.f};
  f32x4 acc[2][4][4];
#pragma unroll
  for (int mh = 0; mh < 2; mh++)
#pragma unroll
    for (int m = 0; m < 4; m++)
#pragma unroll
      for (int n = 0; n < 4; n++) acc[mh][m][n] = fz;

  const int KT = K >> 6;

#pragma unroll
  for (int p = 0; p < 4; ++p) {
    gload_lds16(Abase + (size_t)(p * 64) * K, &As[0][p * 4096 + ldsoff]);
    gload_lds16(Bbase + (size_t)(p * 64) * K, &Bs[0][p * 4096 + ldsoff]);
  }
  asm volatile("s_waitcnt vmcnt(0)" ::: "memory");
  __builtin_amdgcn_s_barrier();

  int nb = 0;
  for (int kt = 0; kt < KT; ++kt) {
    const int knext = (kt + 1) << 6;
    const bool more = (kt + 1) < KT;
#pragma unroll
    for (int p = 0; p < 4; ++p) {
      const int mh = p >> 1, kk = p & 1;
      const int ch = ((kk << 2) | fhi) ^ (fr & 7);
      bf16x8 af[4], bfr[4];
#pragma unroll
      for (int m = 0; m < 4; ++m) {
        const int row = wm * 128 + mh * 64 + m * 16 + fr;
        af[m] = *(const bf16x8*)((const char*)&As[nb][0] + row * 128 + ch * 16);
      }
#pragma unroll
      for (int n = 0; n < 4; ++n) {
        const int row = wn * 64 + n * 16 + fr;
        bfr[n] = *(const bf16x8*)((const char*)&Bs[nb][0] + row * 128 + ch * 16);
      }
      if (more) {
        gload_lds16(Abase + (size_t)(p * 64) * K + knext, &As[nb ^ 1][p * 4096 + ldsoff]);
        gload_lds16(Bbase + (size_t)(p * 64) * K + knext, &Bs[nb ^ 1][p * 4096 + ldsoff]);
      }
      __builtin_amdgcn_s_barrier();
      asm volatile("s_waitcnt lgkmcnt(0)" ::: "memory");
      __builtin_amdgcn_s_setprio(1);
#pragma unroll
      for (int m = 0; m < 4; ++m)
#pragma unroll
        for (int n = 0; n < 4; ++n)
          acc[mh][m][n] = __builtin_amdgcn_mfma_f32_16x16x32_bf16(af[m], bfr[n], acc[mh][m][n], 0, 0, 0);
      __builtin_amdgcn_s_setprio(0);
      __builtin_amdgcn_s_barrier();
    }
    asm volatile("s_waitcnt vmcnt(0)" ::: "memory");
    __builtin_amdgcn_s_barrier();
    nb ^= 1;
  }

#pragma unroll
  for (int mh = 0; mh < 2; ++mh)
#pragma unroll
    for (int m = 0; m < 4; ++m)
#pragma unroll
      for (int n = 0; n < 4; ++n) {
        const int col = n0 + wn * 64 + n * 16 + fr;
        const float bv = bias[col];
#pragma unroll
        for (int r = 0; r < 4; ++r) {
          const int row = m0 + wm * 128 + mh * 64 + m * 16 + fhi * 4 + r;
          const float v = acc[mh][m][n][r] + bv;
          if (MODE == 0)
            ((u16*)C0)[(size_t)row * N + col] = f2bf(v * 0.125f);
          else
            ((float*)C0)[(size_t)row * N + col] = v;
        }
      }
}

// ---------------- fused attention v12: K AND V LDS-resident, 160KB, 8 waves ----
// 512 blocks = 64 bh x 8 q-chunks (XCD-grouped), 512 threads (8 waves x 64
// q-rows; wave tile stays 32 rows x 2 q-tiles). Prologue stages K [512][64]
// AND V^T [64][512] (64KB each) into XOR-swizzled LDS once (one vmcnt(0) +
// one barrier). Main loop: ZERO barriers, ZERO global loads -- K and V both
// served by conflict-free swizzled ds_read_b128, P wave-private swizzled.
// This removes the per-iteration V L2 latency (2 x ~400cy) from the wave's
// serial chain -- the measured bottleneck (r11: wall == 32 x 6.5k cy chain).
// LDS = 64+64+32 = 160KB (AITER precedent m243: 160KB workgroups launch on
// gfx950); 1 block/CU, 8 waves/CU, VGPR budget 256/wave -> no spill risk.
__launch_bounds__(512, 2)
__global__ void attn_kernel(const u16* __restrict__ Q, const u16* __restrict__ Kb,
                            const u16* __restrict__ VT, const float* __restrict__ maskf,
                            u16* __restrict__ O) {
  __shared__ __align__(16) u16 Ks[512 * 64];  // 64KB swizzled K [512 s][64 d]
  __shared__ __align__(16) u16 Vs[64 * 512];  // 64KB swizzled V^T [64 d][512 s]
  __shared__ __align__(16) u16 Ps[8][2048];   // 32KB, 4KB/wave swizzled P[32][64]
  const int tid = threadIdx.x, w = tid >> 6, l = tid & 63;
  const int fr = l & 15, fhi = l >> 4;

  // XCD-aware decode: 512 blocks, 64/XCD -> 8 contiguous bh per XCD
  const int rid = blockIdx.x;
  const int orig = ((rid & 7) << 6) + (rid >> 3);
  const int bh = orig >> 3, qc = orig & 7;
  const int b = bh >> 4, h = bh & 15;

  const u16* Kg = Kb + (size_t)bh * NS * HDIM;   // [512][64]
  const u16* Vg = VT + (size_t)bh * HDIM * NS;   // [64][512]
  const float* mrow = maskf + b * NS;

  // ---- prologue: stage ALL of K and V^T into swizzled LDS (once) ----
  // K: 4096 16B-slots; slot = it*512 + tid; row = slot>>3, c3 = slot&7;
  //    global chunk = c3 ^ (row&7); LDS linear (wave-uniform + lane*16).
  // V: 4096 16B-slots; row = slot>>6 (1KB rows), c6 = slot&63;
  //    global chunk = c6 ^ (row&7)  (XOR on low 3 bits only).
#pragma unroll
  for (int it = 0; it < 8; ++it) {
    const int slot = it * 512 + tid;
    const int r = slot >> 3, c3 = slot & 7;
    const int gc = c3 ^ (r & 7);
    gload_lds16(Kg + (size_t)r * HDIM + gc * 8, &Ks[slot * 8]);
  }
#pragma unroll
  for (int it = 0; it < 8; ++it) {
    const int slot = it * 512 + tid;
    const int r = slot >> 6, c6 = slot & 63;
    const int gc = c6 ^ (r & 7);
    gload_lds16(Vg + (size_t)r * NS + gc * 8, &Vs[slot * 8]);
  }
  asm volatile("s_waitcnt vmcnt(0)" ::: "memory");
  __syncthreads();
  // ---- K,V resident; no barriers, no global loads from here on ----

  u16* Pw = Ps[w];
  const f32x4 fz = {0.f, 0.f, 0.f, 0.f};

#pragma unroll 1
  for (int qt = 0; qt < 2; ++qt) {
    const int rowbase = b * NQ + qc * 512 + w * 64 + qt * 32;

    // Q fragments (B-operand of swapped QK^T)
    bf16x8 qf[2][2];
#pragma unroll
    for (int mt = 0; mt < 2; mt++)
#pragma unroll
      for (int kk = 0; kk < 2; kk++)
        qf[mt][kk] = *(const bf16x8*)&Q[(size_t)(rowbase + mt * 16 + fr) * DIMC +
                                        h * 64 + kk * 32 + fhi * 8];

    float l_run[2] = {0.f, 0.f};
    f32x4 o_acc[2][4];
#pragma unroll
    for (int mt = 0; mt < 2; mt++)
#pragma unroll
      for (int dn = 0; dn < 4; dn++) o_acc[mt][dn] = fz;

#pragma unroll
    for (int t = 0; t < 8; ++t) {
      const int sc = t * 64;

      // S^T = K Q^T : lane holds S^T[s = sc+sn*16+fhi*4+r][q = mt*16+fr]
      f32x4 sacc[2][4];
#pragma unroll
      for (int mt = 0; mt < 2; mt++)
#pragma unroll
        for (int sn = 0; sn < 4; sn++) sacc[mt][sn] = fz;

      __builtin_amdgcn_s_setprio(1);
#pragma unroll
      for (int kk = 0; kk < 2; kk++) {
        bf16x8 kf[4];
#pragma unroll
        for (int sn = 0; sn < 4; sn++) {
          const int row = sc + sn * 16 + fr;
          const int byte = row * 128 + ((((kk << 2) | fhi) ^ (fr & 7)) << 4);
          kf[sn] = *(const bf16x8*)((const char*)&Ks[0] + byte);
        }
#pragma unroll
        for (int sn = 0; sn < 4; sn++)
#pragma unroll
          for (int mt = 0; mt < 2; mt++)
            sacc[mt][sn] = __builtin_amdgcn_mfma_f32_16x16x32_bf16(kf[sn], qf[mt][kk], sacc[mt][sn], 0, 0, 0);
      }
      __builtin_amdgcn_s_setprio(0);

      float4 mv4[4];
#pragma unroll
      for (int sn = 0; sn < 4; sn++)
        mv4[sn] = *(const float4*)&mrow[sc + sn * 16 + fhi * 4];

      // no-max softmax: e = 2^(s*log2e + mask); per-lane partial sums only
#pragma unroll
      for (int mt = 0; mt < 2; mt++) {
        float ls = 0.f;
        const int qrow = mt * 16 + fr;
#pragma unroll
        for (int sn = 0; sn < 4; sn++) {
          const float e0 = EXP2F(fmaf(sacc[mt][sn][0], LOG2E, ((const float*)&mv4[sn])[0]));
          const float e1 = EXP2F(fmaf(sacc[mt][sn][1], LOG2E, ((const float*)&mv4[sn])[1]));
          const float e2 = EXP2F(fmaf(sacc[mt][sn][2], LOG2E, ((const float*)&mv4[sn])[2]));
          const float e3 = EXP2F(fmaf(sacc[mt][sn][3], LOG2E, ((const float*)&mv4[sn])[3]));
          ls += (e0 + e1) + (e2 + e3);
          int byte = qrow * 128 + sn * 32 + fhi * 8;
          byte ^= (qrow & 7) << 4;
          uint2 pk;
          pk.x = pack_bf2(e0, e1);
          pk.y = pack_bf2(e2, e3);
          *(uint2*)((char*)Pw + byte) = pk;
        }
        l_run[mt] += ls;
      }
      asm volatile("s_waitcnt lgkmcnt(0)" ::: "memory");

      // O += P V : P from wave-private swizzled LDS, V from resident swizzled LDS
      __builtin_amdgcn_s_setprio(1);
#pragma unroll
      for (int kk = 0; kk < 2; kk++) {
        bf16x8 vv[4];
#pragma unroll
        for (int dn = 0; dn < 4; dn++) {
          const int row = dn * 16 + fr;
          const int byte = row * 1024 +
              (((sc >> 3) + ((((kk << 2) | fhi) ^ (fr & 7)))) << 4);
          vv[dn] = *(const bf16x8*)((const char*)&Vs[0] + byte);
        }
#pragma unroll
        for (int mt = 0; mt < 2; mt++) {
          int byte = (mt * 16 + fr) * 128 + kk * 64 + fhi * 16;
          byte ^= (fr & 7) << 4;
          const bf16x8 pa = *(const bf16x8*)((char*)Pw + byte);
#pragma unroll
          for (int dn = 0; dn < 4; dn++)
            o_acc[mt][dn] = __builtin_amdgcn_mfma_f32_16x16x32_bf16(pa, vv[dn], o_acc[mt][dn], 0, 0, 0);
        }
      }
      __builtin_amdgcn_s_setprio(0);
    }

    // per-q-tile epilogue: reduce l, normalize, store
#pragma unroll
    for (int mt = 0; mt < 2; mt++) {
      l_run[mt] += __shfl_xor(l_run[mt], 16);
      l_run[mt] += __shfl_xor(l_run[mt], 32);
    }
#pragma unroll
    for (int mt = 0; mt < 2; mt++) {
      float lo[4];
#pragma unroll
      for (int r = 0; r < 4; r++) {
        lo[r] = RCPF(__shfl(l_run[mt], fhi * 4 + r));
      }
#pragma unroll
      for (int dn = 0; dn < 4; dn++)
#pragma unroll
        for (int r = 0; r < 4; r++) {
          const float v = o_acc[mt][dn][r] * lo[r];
          const int row = rowbase + mt * 16 + fhi * 4 + r;
          O[(size_t)row * DIMC + h * 64 + dn * 16 + fr] = f2bf(v);
        }
    }
  }
}

// ---------------- launch ----------------

extern "C" void kernel_launch(void* const* d_in, const int* in_sizes, int n_in,
                              void* d_out, int out_size, void* d_ws, size_t ws_size,
                              hipStream_t stream) {
  const float* x      = (const float*)d_in[0];
  const float* ctx    = (const float*)d_in[1];
  const int*   cmask  = (const int*)d_in[2];
  const float* q_w    = (const float*)d_in[3];
  const float* q_b    = (const float*)d_in[4];
  const float* kv_w   = (const float*)d_in[5];
  const float* kv_b   = (const float*)d_in[6];
  const float* proj_w = (const float*)d_in[7];
  const float* proj_b = (const float*)d_in[8];
  float* out = (float*)d_out;

  char* ws = (char*)d_ws;
  size_t off = 0;
  auto alloc = [&](size_t bytes) {
    void* p = ws + off;
    off += (bytes + 255) & ~(size_t)255;
    return p;
  };
  u16* x_bf   = (u16*)alloc((size_t)16384 * 1024 * 2);
  u16* ctx_bf = (u16*)alloc((size_t)2048 * 1024 * 2);
  u16* qwT    = (u16*)alloc((size_t)1024 * 1024 * 2);
  u16* kvwT   = (u16*)alloc((size_t)2048 * 1024 * 2);
  u16* pwT    = (u16*)alloc((size_t)1024 * 1024 * 2);
  u16* Qb     = (u16*)alloc((size_t)16384 * 1024 * 2);
  u16* Kbuf   = (u16*)alloc((size_t)64 * 512 * 64 * 2);
  u16* VTbuf  = (u16*)alloc((size_t)64 * 64 * 512 * 2);
  u16* Ob     = (u16*)alloc((size_t)16384 * 1024 * 2);
  float* maskf = (float*)alloc((size_t)NB * NS * 4);

  // all preprocessing in one launch
  prep_kernel<<<6664, 256, 0, stream>>>(x, ctx, cmask, q_w, kv_w, proj_w,
                                        x_bf, ctx_bf, qwT, kvwT, pwT, maskf);

  // Q = (x @ q_w + q_b) * 0.125  (bf16 out, attention scale folded) -- 8-phase 256^2
  gemm256<0><<<256, 512, 0, stream>>>(x_bf, qwT, q_b, Qb, 16384, 1024, 1024);
  // KV = ctx @ kv_w + kv_b  (scatter to K / V^T) -- 128^2
  gemm_kv<<<dim3(16, 16), 256, 0, stream>>>(ctx_bf, kvwT, kv_b, Kbuf, VTbuf, 2048, 2048, 1024);
  // attention (K+V LDS-resident, 160KB, 8 waves, barrier-free loop)
  attn_kernel<<<512, 512, 0, stream>>>(Qb, Kbuf, VTbuf, maskf, Ob);
  // out = O @ proj_w + proj_b (f32) -- 8-phase 256^2
  gemm256<2><<<256, 512, 0, stream>>>(Ob, pwT, proj_b, out, 16384, 1024, 1024);
}